// Round 6
// baseline (447.512 us; speedup 1.0000x reference)
//
#include <hip/hip_runtime.h>

#define DEV_INLINE __device__ __forceinline__

// P layout: float P[n_nodes][12]; slots 0..8 accumulate, 9..11 pad so the
// row is 48B and float4-gatherable at +0/+16/+32.

// sh[0..8]: l=0,1,2 real spherical harmonics as in reference _sh (first 9 comps)
static DEV_INLINE void sh_l012(float xx, float yy, float zz, float sh[9]) {
    const float s3  = 1.7320508075688772f;
    const float s5  = 2.23606797749979f;
    const float s15 = 3.872983346207417f;
    float r2 = xx * xx + yy * yy + zz * zz;
    sh[0] = 1.0f;
    sh[1] = s3 * xx;
    sh[2] = s3 * yy;
    sh[3] = s3 * zz;
    sh[4] = s15 * xx * yy;
    sh[5] = s15 * yy * zz;
    sh[6] = 0.5f * s5 * (3.0f * zz * zz - r2);
    sh[7] = s15 * xx * zz;
    sh[8] = 0.5f * s15 * (xx * xx - yy * yy);
}

static DEV_INLINE int lower_bound_i(const int* __restrict__ a, int n, int key) {
    int lo = 0, hi = n;
    while (lo < hi) {
        int mid = (lo + hi) >> 1;
        if (a[mid] < key) lo = mid + 1; else hi = mid;
    }
    return lo;
}

// k0: zero deg+P (absorbs the old hipMemsetAsync), node MLP -> node1/node2,
// atomsInv via binary search, out zero. Grid-stride, 512 blocks (2/CU).
__global__ __launch_bounds__(256)
void k0_init(const float* __restrict__ x, const float* __restrict__ pos,
             const float* __restrict__ W1_0, const float* __restrict__ W1_1,
             const float* __restrict__ W1_2, const float* __restrict__ W2_0,
             const float* __restrict__ W2_1, const float* __restrict__ W2_2,
             const int* __restrict__ batch,
             float4* __restrict__ node1, float2* __restrict__ node2,
             int* __restrict__ deg, float* __restrict__ P,
             float* __restrict__ atomsInv, float* __restrict__ out,
             int n_nodes, int n_mol) {
    __shared__ float ws[90];
    const int t = threadIdx.x;
    const int g = blockIdx.x * blockDim.x + t;
    const int gsz = gridDim.x * blockDim.x;
    // ws = W1 @ W2 per bucket, scaled by 1/sqrt(30)
    const float inv_s30 = 0.18257418583505536f;
    if (t < 30) {
        float s = 0.f;
        for (int u = 0; u < 64; u++) s += W1_0[t * 64 + u] * W2_0[u];
        ws[t] = s * inv_s30;
    } else if (t < 60) {
        int k = t - 30;
        float s = 0.f;
        for (int u = 0; u < 24; u++) s += W1_1[k * 24 + u] * W2_1[u];
        ws[t] = s * inv_s30;
    } else if (t < 90) {
        int k = t - 60;
        float s = 0.f;
        for (int u = 0; u < 16; u++) s += W1_2[k * 16 + u] * W2_2[u];
        ws[t] = s * inv_s30;
    }
    // zeroing (independent of ws) before the sync to overlap
    for (int v = g; v < n_nodes; v += gsz) deg[v] = 0;
    float4* P4 = (float4*)P;
    const int np4 = (n_nodes * 12) >> 2;  // 12 floats/row -> always /4
    const float4 z4 = make_float4(0.f, 0.f, 0.f, 0.f);
    for (int i = g; i < np4; i += gsz) P4[i] = z4;
    __syncthreads();
    for (int v = g; v < n_nodes; v += gsz) {
        const float* xv = x + (size_t)v * 30;
        float s0 = 0.f, s1 = 0.f, s2 = 0.f;
#pragma unroll
        for (int k = 0; k < 30; k++) {
            float xk = xv[k];
            s0 += xk * ws[k];
            s1 += xk * ws[30 + k];
            s2 += xk * ws[60 + k];
        }
        node1[v] = make_float4(pos[v * 3 + 0], pos[v * 3 + 1], pos[v * 3 + 2], s0);
        node2[v] = make_float2(s1, s2);
    }
    if (blockIdx.x == 0) {
        // atoms per mol = lower_bound(m+1) - lower_bound(m) on sorted batch.
        for (int m = t; m < n_mol; m += 256) {
            int lo = lower_bound_i(batch, n_nodes, m);
            int hi = lower_bound_i(batch, n_nodes, m + 1);
            int cnt = hi - lo;
            atomsInv[m] = (cnt > 0) ? rsqrtf((float)cnt) : 0.f;
            out[m] = 0.f;
        }
    }
}

// kE1: hop-1 accumulation. Per edge (s,d): P[d][m] += ea*sh_m(pos_s-pos_d)*b(s),
// deg[d]++. All atomics fire-and-forget (non-returning) -> no dependent chain;
// 1 edge/thread for max TLP. Replaces {rank-atomic + rec scatter + passA}.
__global__ __launch_bounds__(256)
void kE1(const int* __restrict__ esrc, const int* __restrict__ edst,
         const float* __restrict__ eattr,
         const float4* __restrict__ node1, const float2* __restrict__ node2,
         int* __restrict__ deg, float* __restrict__ P, int n_edges) {
    int e = blockIdx.x * blockDim.x + threadIdx.x;
    if (e >= n_edges) return;
    int src = esrc[e];
    int dst = edst[e];
    float ea = eattr[(size_t)e * 10];
    float4 n1s = node1[src];
    float2 n2s = node2[src];
    float4 n1d = node1[dst];
    float sh[9];
    sh_l012(n1s.x - n1d.x, n1s.y - n1d.y, n1s.z - n1d.z, sh);
    atomicAdd(deg + dst, 1);
    float* Pd = P + (size_t)dst * 12;
    atomicAdd(Pd + 0, ea * n1s.w);  // sh[0]==1, b0 in n1s.w
#pragma unroll
    for (int m = 1; m < 4; m++) atomicAdd(Pd + m, ea * sh[m] * n2s.x);
#pragma unroll
    for (int m = 4; m < 9; m++) atomicAdd(Pd + m, ea * sh[m] * n2s.y);
}

// kE2: hop-2 + molecule reduction. 4 edges/thread; per edge gather P[src]
// (3x float4), deg, pos; val = ea*isd_s*(P.sh weighted)*i104*isd_d ->
// LDS mol bin; one 512-bin flush (x atomsInv) per block.
__global__ __launch_bounds__(256)
void kE2(const int* __restrict__ esrc, const int* __restrict__ edst,
         const float* __restrict__ eattr, const int* __restrict__ batch,
         const float4* __restrict__ node1, const float* __restrict__ P,
         const int* __restrict__ deg, const float* __restrict__ atomsInv,
         float* __restrict__ out, int n_edges, int n_mol) {
    __shared__ float smol[512];
    const int t = threadIdx.x;
    smol[t] = 0.f;
    smol[t + 256] = 0.f;
    __syncthreads();
    const float i3 = 0.5773502691896258f;     // 1/sqrt(3)
    const float i5 = 0.4472135954999579f;     // 1/sqrt(5)
    const float i104 = 0.09805806756909202f;  // 1/sqrt(104)
    int e0 = (blockIdx.x * blockDim.x + t) * 4;
#pragma unroll
    for (int k = 0; k < 4; k++) {
        int e = e0 + k;
        if (e >= n_edges) break;
        int src = esrc[e];
        int dst = edst[e];
        float ea = eattr[(size_t)e * 10];
        const float4* Ps = (const float4*)(P + (size_t)src * 12);
        float4 p03 = Ps[0];
        float4 p47 = Ps[1];
        float4 p8x = Ps[2];
        float4 n1s = node1[src];
        float4 n1d = node1[dst];
        int ds = deg[src];
        int dd = deg[dst];
        int mb = batch[dst];
        float sh[9];
        sh_l012(n1s.x - n1d.x, n1s.y - n1d.y, n1s.z - n1d.z, sh);
        float isd_s = (ds > 0) ? rsqrtf((float)ds) : 0.f;
        float isd_d = (dd > 0) ? rsqrtf((float)dd) : 0.f;
        float t1 = sh[1] * p03.y + sh[2] * p03.z + sh[3] * p03.w;
        float t2 = sh[4] * p47.x + sh[5] * p47.y + sh[6] * p47.z +
                   sh[7] * p47.w + sh[8] * p8x.x;
        float val = ea * isd_s * (p03.x + t1 * i3 + t2 * i5) * i104 * isd_d;
        if (mb < 512) atomicAdd(&smol[mb], val);
        else atomicAdd(out + mb, val * atomsInv[mb]);  // safety for n_mol>512
    }
    __syncthreads();
    for (int m = t; m < n_mol && m < 512; m += 256) {
        float v = smol[m];
        if (v != 0.f) atomicAdd(out + m, v * atomsInv[m]);
    }
}

extern "C" void kernel_launch(void* const* d_in, const int* in_sizes, int n_in,
                              void* d_out, int out_size, void* d_ws, size_t ws_size,
                              hipStream_t stream) {
    const float* pos   = (const float*)d_in[0];
    const float* x     = (const float*)d_in[1];
    const float* eattr = (const float*)d_in[2];
    const float* W1_0  = (const float*)d_in[3];
    const float* W1_1  = (const float*)d_in[4];
    const float* W1_2  = (const float*)d_in[5];
    const float* W2_0  = (const float*)d_in[6];
    const float* W2_1  = (const float*)d_in[7];
    const float* W2_2  = (const float*)d_in[8];
    const int* esrc  = (const int*)d_in[9];
    const int* edst  = (const int*)d_in[10];
    const int* batch = (const int*)d_in[11];

    const int n_edges = in_sizes[9];   // 600000
    const int n_nodes = in_sizes[11];  // 50000
    const int n_mol   = out_size;      // 512
    float* out = (float*)d_out;

    const int BS = 256;
    const int NB0 = 512;                                // k0: grid-stride, 2/CU
    const int EB1 = (n_edges + BS - 1) / BS;            // 2344, 1 edge/thread
    const int EB2 = (n_edges + 4 * BS - 1) / (4 * BS);  // 586, 4 edges/thread

    // Workspace layout (zeroing done inside k0 -> no memset dispatch).
    char* ws = (char*)d_ws;
    size_t off = 0;
    auto carve = [&](size_t bytes) {
        size_t o = off;
        off = (off + bytes + 255) & ~(size_t)255;
        return o;
    };
    size_t off_deg  = carve((size_t)n_nodes * sizeof(int));
    size_t off_P    = carve((size_t)n_nodes * 12 * sizeof(float));  // 2.4 MB
    size_t off_ainv = carve((size_t)n_mol * sizeof(float));
    size_t off_n1   = carve((size_t)n_nodes * sizeof(float4));
    size_t off_n2   = carve((size_t)n_nodes * sizeof(float2));
    (void)ws_size;

    int*    deg      = (int*)(ws + off_deg);
    float*  P        = (float*)(ws + off_P);
    float*  atomsInv = (float*)(ws + off_ainv);
    float4* node1    = (float4*)(ws + off_n1);
    float2* node2    = (float2*)(ws + off_n2);

    k0_init<<<NB0, BS, 0, stream>>>(x, pos, W1_0, W1_1, W1_2, W2_0, W2_1, W2_2,
                                    batch, node1, node2, deg, P, atomsInv, out,
                                    n_nodes, n_mol);
    kE1<<<EB1, BS, 0, stream>>>(esrc, edst, eattr, node1, node2, deg, P, n_edges);
    kE2<<<EB2, BS, 0, stream>>>(esrc, edst, eattr, batch, node1, P, deg,
                                atomsInv, out, n_edges, n_mol);
}